// Round 8
// baseline (336.777 us; speedup 1.0000x reference)
//
#include <hip/hip_runtime.h>
#include <hip/hip_bf16.h>

constexpr int BATCH = 8;
constexpr int N = 2048;
constexpr int D = 512;

using short8 = __attribute__((ext_vector_type(8))) short;
using half8 = __attribute__((ext_vector_type(8))) _Float16;
using floatx4 = __attribute__((ext_vector_type(4))) float;

// ---------------------------------------------------------------------------
// Kernel 0: fp32 -> fp16 (h, l) Dekker split.  x = h + l + eps, eps ~ 2^-22|x|.
// ---------------------------------------------------------------------------
__global__ __launch_bounds__(256) void convert_kernel(const float* __restrict__ in,
                                                      unsigned short* __restrict__ hi,
                                                      unsigned short* __restrict__ lo) {
    size_t base = ((size_t)blockIdx.x * 256 + threadIdx.x) * 8;
    float v[8];
    *(float4*)(v) = *(const float4*)(in + base);
    *(float4*)(v + 4) = *(const float4*)(in + base + 4);
    short8 h, l;
#pragma unroll
    for (int e = 0; e < 8; ++e) {
        _Float16 hh = (_Float16)v[e];            // RNE
        float r = v[e] - (float)hh;              // exact in fp32
        _Float16 ll = (_Float16)r;
        h[e] = __builtin_bit_cast(short, hh);
        l[e] = __builtin_bit_cast(short, ll);
    }
    *(short8*)(hi + base) = h;
    *(short8*)(lo + base) = l;
}

// ---------------------------------------------------------------------------
// Kernel 1: per-batch prefix sum of boundaries -> community ids,
//           plus zeroing of the stats accumulators (replaces hipMemsetAsync).
// ---------------------------------------------------------------------------
__global__ __launch_bounds__(256) void scan_kernel(const int* __restrict__ b,
                                                   int* __restrict__ comm,
                                                   float* __restrict__ stats /*3*BATCH*N*/) {
    int batch = blockIdx.x;
    int t = threadIdx.x;

    // zero ssq|sm|bs: 3*8*2048 floats across 8 blocks x 256 threads = 24 each
    {
        int idx = batch * 256 + t;
        float* p = stats;
#pragma unroll
        for (int u = 0; u < 24; ++u) p[idx + u * 2048] = 0.0f;
    }

    const int* bb = b + batch * N;
    int* cc = comm + batch * N;

    int vals[8];
    int s = 0;
#pragma unroll
    for (int u = 0; u < 8; ++u) { vals[u] = bb[t * 8 + u]; s += vals[u]; }

    __shared__ int ps[256];
    ps[t] = s;
    __syncthreads();
    for (int off = 1; off < 256; off <<= 1) {
        int v = (t >= off) ? ps[t - off] : 0;
        __syncthreads();
        ps[t] += v;
        __syncthreads();
    }
    int run = (t > 0) ? ps[t - 1] : 0;
#pragma unroll
    for (int u = 0; u < 8; ++u) { run += vals[u]; cc[t * 8 + u] = run; }
}

// ---------------------------------------------------------------------------
// Kernel 2: MFMA fp16-split G = R*R^T, symmetric (upper-triangular block pairs),
//   fused per-row stats. 128x128 tile, 4 waves of 64x64, BK=32, 16x16x32 f16.
//   Off-diagonal tiles also emit COLUMN sums (= row stats of the mirror tile).
//   LDS slot swizzle f(r) = (r>>1)&3 (bank base is 16r mod 32, period 2 in r).
//   launch_bounds(256,4): 4 blocks/CU (16 waves) to hide barrier drains.
// ---------------------------------------------------------------------------
__global__ __launch_bounds__(256, 4) void gemm_mfma(
        const unsigned short* __restrict__ Hhi, const unsigned short* __restrict__ Hlo,
        const int* __restrict__ comm,
        float* __restrict__ ssq, float* __restrict__ sm, float* __restrict__ bs) {
    int batch = blockIdx.z;

    // decode triangular pair index -> (bi, bj), bi <= bj
    int t = blockIdx.x;
    int bi = 0;
    while (t >= (16 - bi)) { t -= (16 - bi); ++bi; }
    int bj = bi + t;
    bool diag = (bi == bj);
    int i0 = bi * 128, j0 = bj * 128;

    __shared__ unsigned short sAhi[4096], sAlo[4096], sBhi[4096], sBlo[4096];
    __shared__ int sci[128], scj[128];

    int tid = threadIdx.x;
    const int* cm = comm + batch * N;
    if (tid < 128) { sci[tid] = cm[i0 + tid]; scj[tid] = cm[j0 + tid]; }

    const size_t bo = (size_t)batch * N * D;
    int srow = tid >> 2;                         // 0..63 (LDS row within half)
    int kg = (tid & 3) ^ ((srow >> 1) & 3);      // pre-swizzled source k-group
    size_t gA0 = bo + (size_t)(i0 + srow) * D + kg * 8;
    size_t gA1 = gA0 + (size_t)64 * D;
    size_t gB0 = bo + (size_t)(j0 + srow) * D + kg * 8;
    size_t gB1 = gB0 + (size_t)64 * D;

    int lane = tid & 63;
    int wv = tid >> 6;
    int wrow = wv >> 1, wcol = wv & 1;           // 2x2 waves of 64x64
    int l15 = lane & 15, lhi = lane >> 4;

    // fragment LDS byte offsets (fixed across k-steps)
    int offA[4], offB[4];
#pragma unroll
    for (int m = 0; m < 4; ++m) {
        int r = wrow * 64 + m * 16 + l15;
        offA[m] = r * 64 + ((lhi ^ ((r >> 1) & 3)) << 4);
        int c = wcol * 64 + m * 16 + l15;
        offB[m] = c * 64 + ((lhi ^ ((c >> 1) & 3)) << 4);
    }

    floatx4 acc[4][4];
#pragma unroll
    for (int m = 0; m < 4; ++m)
#pragma unroll
        for (int n = 0; n < 4; ++n) acc[m][n] = (floatx4){0.f, 0.f, 0.f, 0.f};

    int wbyte = tid * 16;                        // linear ds_write offset

    // prologue: load tile 0 into registers
    short8 rAh0 = *(const short8*)(Hhi + gA0);
    short8 rAh1 = *(const short8*)(Hhi + gA1);
    short8 rAl0 = *(const short8*)(Hlo + gA0);
    short8 rAl1 = *(const short8*)(Hlo + gA1);
    short8 rBh0 = *(const short8*)(Hhi + gB0);
    short8 rBh1 = *(const short8*)(Hhi + gB1);
    short8 rBl0 = *(const short8*)(Hlo + gB0);
    short8 rBl1 = *(const short8*)(Hlo + gB1);

#pragma unroll 1
    for (int kt = 0; kt < 16; ++kt) {
        // stage current tile to LDS
        *(short8*)((char*)sAhi + wbyte) = rAh0;
        *(short8*)((char*)sAhi + wbyte + 4096) = rAh1;
        *(short8*)((char*)sAlo + wbyte) = rAl0;
        *(short8*)((char*)sAlo + wbyte + 4096) = rAl1;
        *(short8*)((char*)sBhi + wbyte) = rBh0;
        *(short8*)((char*)sBhi + wbyte + 4096) = rBh1;
        *(short8*)((char*)sBlo + wbyte) = rBl0;
        *(short8*)((char*)sBlo + wbyte + 4096) = rBl1;
        __syncthreads();

        // issue next tile's global loads (latency hides under MFMA below)
        if (kt < 15) {
            size_t k = (size_t)(kt + 1) * 32;
            rAh0 = *(const short8*)(Hhi + gA0 + k);
            rAh1 = *(const short8*)(Hhi + gA1 + k);
            rAl0 = *(const short8*)(Hlo + gA0 + k);
            rAl1 = *(const short8*)(Hlo + gA1 + k);
            rBh0 = *(const short8*)(Hhi + gB0 + k);
            rBh1 = *(const short8*)(Hhi + gB1 + k);
            rBl0 = *(const short8*)(Hlo + gB0 + k);
            rBl1 = *(const short8*)(Hlo + gB1 + k);
        }

        half8 ah[4], al[4], bh[4], bl[4];
#pragma unroll
        for (int m = 0; m < 4; ++m) {
            ah[m] = *(const half8*)((const char*)sAhi + offA[m]);
            al[m] = *(const half8*)((const char*)sAlo + offA[m]);
            bh[m] = *(const half8*)((const char*)sBhi + offB[m]);
            bl[m] = *(const half8*)((const char*)sBlo + offB[m]);
        }
#pragma unroll
        for (int m = 0; m < 4; ++m)
#pragma unroll
            for (int n = 0; n < 4; ++n) {
                acc[m][n] = __builtin_amdgcn_mfma_f32_16x16x32_f16(ah[m], bh[n], acc[m][n], 0, 0, 0);
                acc[m][n] = __builtin_amdgcn_mfma_f32_16x16x32_f16(ah[m], bl[n], acc[m][n], 0, 0, 0);
                acc[m][n] = __builtin_amdgcn_mfma_f32_16x16x32_f16(al[m], bh[n], acc[m][n], 0, 0, 0);
            }
        __syncthreads();
    }

    // epilogue: row stats (sum over this tile's cols) + column stats for the
    // mirror rows when off-diagonal (G symmetric; hh+hl+lh is symmetric).
    float* pssq = ssq + batch * N;
    float* psm = sm + batch * N;
    float* pbs = bs + batch * N;

    int cjv[4];
#pragma unroll
    for (int n = 0; n < 4; ++n) cjv[n] = scj[wcol * 64 + n * 16 + l15];

    float cq[4] = {0.f, 0.f, 0.f, 0.f};
    float cs[4] = {0.f, 0.f, 0.f, 0.f};
    float cb[4] = {0.f, 0.f, 0.f, 0.f};

#pragma unroll
    for (int m = 0; m < 4; ++m) {
#pragma unroll
        for (int rr = 0; rr < 4; ++rr) {
            int rloc = wrow * 64 + m * 16 + lhi * 4 + rr;   // C layout: row=(l>>4)*4+reg
            int civ = sci[rloc];
            float vq = 0.f, vs = 0.f, vb = 0.f;
#pragma unroll
            for (int n = 0; n < 4; ++n) {
                float g = acc[m][n][rr];
                float gq = g * g;
                float gb = (civ == cjv[n]) ? g : 0.f;
                vq += gq; vs += g; vb += gb;
                cq[n] += gq; cs[n] += g; cb[n] += gb;
            }
#pragma unroll
            for (int msk = 8; msk >= 1; msk >>= 1) {
                vq += __shfl_xor(vq, msk);
                vs += __shfl_xor(vs, msk);
                vb += __shfl_xor(vb, msk);
            }
            if (l15 == 0) {
                atomicAdd(&pssq[i0 + rloc], vq);
                atomicAdd(&psm[i0 + rloc], vs);
                atomicAdd(&pbs[i0 + rloc], vb);
            }
        }
    }

    if (!diag) {
#pragma unroll
        for (int n = 0; n < 4; ++n) {
            cq[n] += __shfl_xor(cq[n], 16); cq[n] += __shfl_xor(cq[n], 32);
            cs[n] += __shfl_xor(cs[n], 16); cs[n] += __shfl_xor(cs[n], 32);
            cb[n] += __shfl_xor(cb[n], 16); cb[n] += __shfl_xor(cb[n], 32);
            if (lhi == 0) {
                int col = j0 + wcol * 64 + n * 16 + l15;
                atomicAdd(&pssq[col], cq[n]);
                atomicAdd(&psm[col], cs[n]);
                atomicAdd(&pbs[col], cb[n]);
            }
        }
    }
}

// ---------------------------------------------------------------------------
// Kernel 3: per-batch finalize -> modularity + conductance (1024 threads)
// ---------------------------------------------------------------------------
__global__ __launch_bounds__(1024) void finalize(const float* __restrict__ ssq,
                                                 const float* __restrict__ sm,
                                                 const float* __restrict__ bs,
                                                 const int* __restrict__ comm,
                                                 float* __restrict__ out) {
    int batch = blockIdx.x;
    const float* pssq = ssq + batch * N;
    const float* psm = sm + batch * N;
    const float* pbs = bs + batch * N;
    const int* pcomm = comm + batch * N;
    int tid = threadIdx.x;

    __shared__ float sWc[N + 1];
    __shared__ float sTc[N + 1];
    __shared__ int sCnt[N + 1];

    for (int c = tid; c < N + 1; c += 1024) { sWc[c] = 0.0f; sTc[c] = 0.0f; sCnt[c] = 0; }
    __syncthreads();

    float totalLocal = 0.0f;
    for (int i = tid; i < N; i += 1024) {
        float r = sqrtf(pssq[i]);
        r = fmaxf(r, 1e-12f);
        float deg = psm[i] / r;
        float bn = pbs[i] / r;
        int c = pcomm[i];
        atomicAdd(&sTc[c], deg);
        atomicAdd(&sWc[c], bn);
        atomicAdd(&sCnt[c], 1);
        totalLocal += deg;
    }
    __syncthreads();

    float sumW = 0.0f, sumT2 = 0.0f, condSum = 0.0f, ncomm = 0.0f;
    for (int c = tid; c < N + 1; c += 1024) {
        if (sCnt[c] > 0) {
            float W = sWc[c];
            float T = sTc[c];
            sumW += W;
            sumT2 += T * T;
            float between = T - W;
            condSum += between / (2.0f * W + between + 1e-10f);
            ncomm += 1.0f;
        }
    }

    float vals[5] = {totalLocal, sumW, sumT2, condSum, ncomm};
#pragma unroll
    for (int v = 0; v < 5; ++v)
#pragma unroll
        for (int m = 32; m >= 1; m >>= 1) vals[v] += __shfl_xor(vals[v], m);

    __shared__ float part[5][16];
    int wid = tid >> 6;
    if ((tid & 63) == 0) {
#pragma unroll
        for (int v = 0; v < 5; ++v) part[v][wid] = vals[v];
    }
    __syncthreads();

    if (tid == 0) {
        float red[5];
#pragma unroll
        for (int v = 0; v < 5; ++v) {
            float a = 0.f;
            for (int w = 0; w < 16; ++w) a += part[v][w];
            red[v] = a;
        }
        float total = red[0];
        float mod = (red[1] - red[2] / total) / total;
        float cond = red[3] / fmaxf(red[4], 1.0f);
        out[batch] = mod;
        out[BATCH + batch] = cond;
    }
}

// ---------------------------------------------------------------------------
extern "C" void kernel_launch(void* const* d_in, const int* in_sizes, int n_in,
                              void* d_out, int out_size, void* d_ws, size_t ws_size,
                              hipStream_t stream) {
    const float* rep = (const float*)d_in[0];
    const int* bnd = (const int*)d_in[1];
    float* out = (float*)d_out;

    // ws layout: ssq | sm | bs | comm | Hhi | Hlo
    float* ssq = (float*)d_ws;
    float* sm = ssq + BATCH * N;
    float* bs = sm + BATCH * N;
    int* comm = (int*)(bs + BATCH * N);
    unsigned short* Hhi = (unsigned short*)((char*)d_ws + 256 * 1024);
    unsigned short* Hlo = Hhi + (size_t)BATCH * N * D;

    convert_kernel<<<(BATCH * N * D) / (256 * 8), 256, 0, stream>>>(rep, Hhi, Hlo);
    scan_kernel<<<BATCH, 256, 0, stream>>>(bnd, comm, ssq);

    dim3 grid(136, 1, BATCH);   // upper-triangular block pairs
    gemm_mfma<<<grid, 256, 0, stream>>>(Hhi, Hlo, comm, ssq, sm, bs);

    finalize<<<BATCH, 1024, 0, stream>>>(ssq, sm, bs, comm, out);
}

// Round 9
// 168.152 us; speedup vs baseline: 2.0028x; 2.0028x over previous
//
#include <hip/hip_runtime.h>
#include <hip/hip_bf16.h>

constexpr int BATCH = 8;
constexpr int N = 2048;
constexpr int D = 512;

using short8 = __attribute__((ext_vector_type(8))) short;
using half8 = __attribute__((ext_vector_type(8))) _Float16;
using floatx4 = __attribute__((ext_vector_type(4))) float;

// ---------------------------------------------------------------------------
// Kernel 0: fp32 -> fp16 (h, l) Dekker split.  x = h + l + eps, eps ~ 2^-22|x|.
// ---------------------------------------------------------------------------
__global__ __launch_bounds__(256) void convert_kernel(const float* __restrict__ in,
                                                      unsigned short* __restrict__ hi,
                                                      unsigned short* __restrict__ lo) {
    size_t base = ((size_t)blockIdx.x * 256 + threadIdx.x) * 8;
    float v[8];
    *(float4*)(v) = *(const float4*)(in + base);
    *(float4*)(v + 4) = *(const float4*)(in + base + 4);
    short8 h, l;
#pragma unroll
    for (int e = 0; e < 8; ++e) {
        _Float16 hh = (_Float16)v[e];            // RNE
        float r = v[e] - (float)hh;              // exact in fp32
        _Float16 ll = (_Float16)r;
        h[e] = __builtin_bit_cast(short, hh);
        l[e] = __builtin_bit_cast(short, ll);
    }
    *(short8*)(hi + base) = h;
    *(short8*)(lo + base) = l;
}

// ---------------------------------------------------------------------------
// Kernel 1: per-batch prefix sum of boundaries -> community ids,
//           plus zeroing of the stats accumulators (replaces hipMemsetAsync).
// ---------------------------------------------------------------------------
__global__ __launch_bounds__(256) void scan_kernel(const int* __restrict__ b,
                                                   int* __restrict__ comm,
                                                   float* __restrict__ stats /*3*BATCH*N*/) {
    int batch = blockIdx.x;
    int t = threadIdx.x;

    // zero ssq|sm|bs: 3*8*2048 floats across 8 blocks x 256 threads = 24 each
    {
        int idx = batch * 256 + t;
        float* p = stats;
#pragma unroll
        for (int u = 0; u < 24; ++u) p[idx + u * 2048] = 0.0f;
    }

    const int* bb = b + batch * N;
    int* cc = comm + batch * N;

    int vals[8];
    int s = 0;
#pragma unroll
    for (int u = 0; u < 8; ++u) { vals[u] = bb[t * 8 + u]; s += vals[u]; }

    __shared__ int ps[256];
    ps[t] = s;
    __syncthreads();
    for (int off = 1; off < 256; off <<= 1) {
        int v = (t >= off) ? ps[t - off] : 0;
        __syncthreads();
        ps[t] += v;
        __syncthreads();
    }
    int run = (t > 0) ? ps[t - 1] : 0;
#pragma unroll
    for (int u = 0; u < 8; ++u) { run += vals[u]; cc[t * 8 + u] = run; }
}

// ---------------------------------------------------------------------------
// Kernel 2: MFMA fp16-split G = R*R^T, symmetric (upper-triangular block pairs),
//   fused per-row stats. 128x128 tile, 4 waves of 64x64, BK=32, 16x16x32 f16.
//   Off-diagonal tiles also emit COLUMN sums (= row stats of the mirror tile).
//   LDS slot swizzle f(r) = (r>>1)&3 (bank base is 16r mod 32, period 2 in r).
//   launch_bounds(256,3): unified VGPR+AGPR cap ~170 covers 84+64=148 (NO
//   spill; (256,4)'s 128-cap forced staging spills -> 3x regression in r8).
// ---------------------------------------------------------------------------
__global__ __launch_bounds__(256, 3) void gemm_mfma(
        const unsigned short* __restrict__ Hhi, const unsigned short* __restrict__ Hlo,
        const int* __restrict__ comm,
        float* __restrict__ ssq, float* __restrict__ sm, float* __restrict__ bs) {
    int batch = blockIdx.z;

    // decode triangular pair index -> (bi, bj), bi <= bj
    int t = blockIdx.x;
    int bi = 0;
    while (t >= (16 - bi)) { t -= (16 - bi); ++bi; }
    int bj = bi + t;
    bool diag = (bi == bj);
    int i0 = bi * 128, j0 = bj * 128;

    __shared__ unsigned short sAhi[4096], sAlo[4096], sBhi[4096], sBlo[4096];
    __shared__ int sci[128], scj[128];

    int tid = threadIdx.x;
    const int* cm = comm + batch * N;
    if (tid < 128) { sci[tid] = cm[i0 + tid]; scj[tid] = cm[j0 + tid]; }

    const size_t bo = (size_t)batch * N * D;
    int srow = tid >> 2;                         // 0..63 (LDS row within half)
    int kg = (tid & 3) ^ ((srow >> 1) & 3);      // pre-swizzled source k-group
    size_t gA0 = bo + (size_t)(i0 + srow) * D + kg * 8;
    size_t gA1 = gA0 + (size_t)64 * D;
    size_t gB0 = bo + (size_t)(j0 + srow) * D + kg * 8;
    size_t gB1 = gB0 + (size_t)64 * D;

    int lane = tid & 63;
    int wv = tid >> 6;
    int wrow = wv >> 1, wcol = wv & 1;           // 2x2 waves of 64x64
    int l15 = lane & 15, lhi = lane >> 4;

    // fragment LDS byte offsets (fixed across k-steps)
    int offA[4], offB[4];
#pragma unroll
    for (int m = 0; m < 4; ++m) {
        int r = wrow * 64 + m * 16 + l15;
        offA[m] = r * 64 + ((lhi ^ ((r >> 1) & 3)) << 4);
        int c = wcol * 64 + m * 16 + l15;
        offB[m] = c * 64 + ((lhi ^ ((c >> 1) & 3)) << 4);
    }

    floatx4 acc[4][4];
#pragma unroll
    for (int m = 0; m < 4; ++m)
#pragma unroll
        for (int n = 0; n < 4; ++n) acc[m][n] = (floatx4){0.f, 0.f, 0.f, 0.f};

    int wbyte = tid * 16;                        // linear ds_write offset

    // prologue: load tile 0 into registers
    short8 rAh0 = *(const short8*)(Hhi + gA0);
    short8 rAh1 = *(const short8*)(Hhi + gA1);
    short8 rAl0 = *(const short8*)(Hlo + gA0);
    short8 rAl1 = *(const short8*)(Hlo + gA1);
    short8 rBh0 = *(const short8*)(Hhi + gB0);
    short8 rBh1 = *(const short8*)(Hhi + gB1);
    short8 rBl0 = *(const short8*)(Hlo + gB0);
    short8 rBl1 = *(const short8*)(Hlo + gB1);

#pragma unroll 1
    for (int kt = 0; kt < 16; ++kt) {
        // stage current tile to LDS
        *(short8*)((char*)sAhi + wbyte) = rAh0;
        *(short8*)((char*)sAhi + wbyte + 4096) = rAh1;
        *(short8*)((char*)sAlo + wbyte) = rAl0;
        *(short8*)((char*)sAlo + wbyte + 4096) = rAl1;
        *(short8*)((char*)sBhi + wbyte) = rBh0;
        *(short8*)((char*)sBhi + wbyte + 4096) = rBh1;
        *(short8*)((char*)sBlo + wbyte) = rBl0;
        *(short8*)((char*)sBlo + wbyte + 4096) = rBl1;
        __syncthreads();

        // issue next tile's global loads (latency hides under MFMA below)
        if (kt < 15) {
            size_t k = (size_t)(kt + 1) * 32;
            rAh0 = *(const short8*)(Hhi + gA0 + k);
            rAh1 = *(const short8*)(Hhi + gA1 + k);
            rAl0 = *(const short8*)(Hlo + gA0 + k);
            rAl1 = *(const short8*)(Hlo + gA1 + k);
            rBh0 = *(const short8*)(Hhi + gB0 + k);
            rBh1 = *(const short8*)(Hhi + gB1 + k);
            rBl0 = *(const short8*)(Hlo + gB0 + k);
            rBl1 = *(const short8*)(Hlo + gB1 + k);
        }

        half8 ah[4], al[4], bh[4], bl[4];
#pragma unroll
        for (int m = 0; m < 4; ++m) {
            ah[m] = *(const half8*)((const char*)sAhi + offA[m]);
            al[m] = *(const half8*)((const char*)sAlo + offA[m]);
            bh[m] = *(const half8*)((const char*)sBhi + offB[m]);
            bl[m] = *(const half8*)((const char*)sBlo + offB[m]);
        }
#pragma unroll
        for (int m = 0; m < 4; ++m)
#pragma unroll
            for (int n = 0; n < 4; ++n) {
                acc[m][n] = __builtin_amdgcn_mfma_f32_16x16x32_f16(ah[m], bh[n], acc[m][n], 0, 0, 0);
                acc[m][n] = __builtin_amdgcn_mfma_f32_16x16x32_f16(ah[m], bl[n], acc[m][n], 0, 0, 0);
                acc[m][n] = __builtin_amdgcn_mfma_f32_16x16x32_f16(al[m], bh[n], acc[m][n], 0, 0, 0);
            }
        __syncthreads();
    }

    // epilogue: row stats (sum over this tile's cols) + column stats for the
    // mirror rows when off-diagonal (G symmetric; hh+hl+lh is symmetric).
    float* pssq = ssq + batch * N;
    float* psm = sm + batch * N;
    float* pbs = bs + batch * N;

    int cjv[4];
#pragma unroll
    for (int n = 0; n < 4; ++n) cjv[n] = scj[wcol * 64 + n * 16 + l15];

    float cq[4] = {0.f, 0.f, 0.f, 0.f};
    float cs[4] = {0.f, 0.f, 0.f, 0.f};
    float cb[4] = {0.f, 0.f, 0.f, 0.f};

#pragma unroll
    for (int m = 0; m < 4; ++m) {
#pragma unroll
        for (int rr = 0; rr < 4; ++rr) {
            int rloc = wrow * 64 + m * 16 + lhi * 4 + rr;   // C layout: row=(l>>4)*4+reg
            int civ = sci[rloc];
            float vq = 0.f, vs = 0.f, vb = 0.f;
#pragma unroll
            for (int n = 0; n < 4; ++n) {
                float g = acc[m][n][rr];
                float gq = g * g;
                float gb = (civ == cjv[n]) ? g : 0.f;
                vq += gq; vs += g; vb += gb;
                cq[n] += gq; cs[n] += g; cb[n] += gb;
            }
#pragma unroll
            for (int msk = 8; msk >= 1; msk >>= 1) {
                vq += __shfl_xor(vq, msk);
                vs += __shfl_xor(vs, msk);
                vb += __shfl_xor(vb, msk);
            }
            if (l15 == 0) {
                atomicAdd(&pssq[i0 + rloc], vq);
                atomicAdd(&psm[i0 + rloc], vs);
                atomicAdd(&pbs[i0 + rloc], vb);
            }
        }
    }

    if (!diag) {
#pragma unroll
        for (int n = 0; n < 4; ++n) {
            cq[n] += __shfl_xor(cq[n], 16); cq[n] += __shfl_xor(cq[n], 32);
            cs[n] += __shfl_xor(cs[n], 16); cs[n] += __shfl_xor(cs[n], 32);
            cb[n] += __shfl_xor(cb[n], 16); cb[n] += __shfl_xor(cb[n], 32);
            if (lhi == 0) {
                int col = j0 + wcol * 64 + n * 16 + l15;
                atomicAdd(&pssq[col], cq[n]);
                atomicAdd(&psm[col], cs[n]);
                atomicAdd(&pbs[col], cb[n]);
            }
        }
    }
}

// ---------------------------------------------------------------------------
// Kernel 3: per-batch finalize -> modularity + conductance (1024 threads)
// ---------------------------------------------------------------------------
__global__ __launch_bounds__(1024) void finalize(const float* __restrict__ ssq,
                                                 const float* __restrict__ sm,
                                                 const float* __restrict__ bs,
                                                 const int* __restrict__ comm,
                                                 float* __restrict__ out) {
    int batch = blockIdx.x;
    const float* pssq = ssq + batch * N;
    const float* psm = sm + batch * N;
    const float* pbs = bs + batch * N;
    const int* pcomm = comm + batch * N;
    int tid = threadIdx.x;

    __shared__ float sWc[N + 1];
    __shared__ float sTc[N + 1];
    __shared__ int sCnt[N + 1];

    for (int c = tid; c < N + 1; c += 1024) { sWc[c] = 0.0f; sTc[c] = 0.0f; sCnt[c] = 0; }
    __syncthreads();

    float totalLocal = 0.0f;
    for (int i = tid; i < N; i += 1024) {
        float r = sqrtf(pssq[i]);
        r = fmaxf(r, 1e-12f);
        float deg = psm[i] / r;
        float bn = pbs[i] / r;
        int c = pcomm[i];
        atomicAdd(&sTc[c], deg);
        atomicAdd(&sWc[c], bn);
        atomicAdd(&sCnt[c], 1);
        totalLocal += deg;
    }
    __syncthreads();

    float sumW = 0.0f, sumT2 = 0.0f, condSum = 0.0f, ncomm = 0.0f;
    for (int c = tid; c < N + 1; c += 1024) {
        if (sCnt[c] > 0) {
            float W = sWc[c];
            float T = sTc[c];
            sumW += W;
            sumT2 += T * T;
            float between = T - W;
            condSum += between / (2.0f * W + between + 1e-10f);
            ncomm += 1.0f;
        }
    }

    float vals[5] = {totalLocal, sumW, sumT2, condSum, ncomm};
#pragma unroll
    for (int v = 0; v < 5; ++v)
#pragma unroll
        for (int m = 32; m >= 1; m >>= 1) vals[v] += __shfl_xor(vals[v], m);

    __shared__ float part[5][16];
    int wid = tid >> 6;
    if ((tid & 63) == 0) {
#pragma unroll
        for (int v = 0; v < 5; ++v) part[v][wid] = vals[v];
    }
    __syncthreads();

    if (tid == 0) {
        float red[5];
#pragma unroll
        for (int v = 0; v < 5; ++v) {
            float a = 0.f;
            for (int w = 0; w < 16; ++w) a += part[v][w];
            red[v] = a;
        }
        float total = red[0];
        float mod = (red[1] - red[2] / total) / total;
        float cond = red[3] / fmaxf(red[4], 1.0f);
        out[batch] = mod;
        out[BATCH + batch] = cond;
    }
}

// ---------------------------------------------------------------------------
extern "C" void kernel_launch(void* const* d_in, const int* in_sizes, int n_in,
                              void* d_out, int out_size, void* d_ws, size_t ws_size,
                              hipStream_t stream) {
    const float* rep = (const float*)d_in[0];
    const int* bnd = (const int*)d_in[1];
    float* out = (float*)d_out;

    // ws layout: ssq | sm | bs | comm | Hhi | Hlo
    float* ssq = (float*)d_ws;
    float* sm = ssq + BATCH * N;
    float* bs = sm + BATCH * N;
    int* comm = (int*)(bs + BATCH * N);
    unsigned short* Hhi = (unsigned short*)((char*)d_ws + 256 * 1024);
    unsigned short* Hlo = Hhi + (size_t)BATCH * N * D;

    convert_kernel<<<(BATCH * N * D) / (256 * 8), 256, 0, stream>>>(rep, Hhi, Hlo);
    scan_kernel<<<BATCH, 256, 0, stream>>>(bnd, comm, ssq);

    dim3 grid(136, 1, BATCH);   // upper-triangular block pairs
    gemm_mfma<<<grid, 256, 0, stream>>>(Hhi, Hlo, comm, ssq, sm, bs);

    finalize<<<BATCH, 1024, 0, stream>>>(ssq, sm, bs, comm, out);
}